// Round 7
// baseline (233.754 us; speedup 1.0000x reference)
//
#include <hip/hip_runtime.h>
#include <stdint.h>

#define BATCH 8
#define NCLS 80
#define MAXDET 100
#define CAP 1024
#define NBINS 10240          // keys 0..10036 (score 1.0) fit without clamping
#define CHUNKB 40            // 256 threads * 40 bins = 10240
#define BASEKEY (0x3D4CCCCDu >> 12)   // float bits of 0.05f >> 12

// ---------------- Kernel 0: zero per-call state ----------------
__global__ void zero_kernel(uint32_t* __restrict__ ghist, uint32_t* __restrict__ ctr,
                            uint32_t* __restrict__ Tb) {
  int i = blockIdx.x * blockDim.x + threadIdx.x;
  if (i < BATCH * NBINS) ghist[i] = 0;
  if (i < BATCH) { ctr[i] = 0; Tb[i] = NBINS; }
}

// ---------------- Kernel 1: scores, two-pass row-per-thread ----------------
// Pass A: running max (order-exact). Pass B: reload row (L2/L3 hit) and
// accumulate the numpy-pairwise r8 sums in the EXACT original order.
// Low VGPR (no x[80] array) -> high occupancy -> memory parallelism.
__global__ __launch_bounds__(256, 6)
void scores_kernel(const float* __restrict__ cls,
                   float* __restrict__ scores,
                   uint32_t* __restrict__ ghist, int N, int BN) {
  int r = blockIdx.x * 256 + threadIdx.x;
  if (r >= BN) return;
  const float4* p = (const float4*)(cls + (size_t)r * NCLS);

  // pass A: max over the row (fmax is exact; any order)
  float4 v0 = p[0];
  float m = fmaxf(fmaxf(v0.x, v0.y), fmaxf(v0.z, v0.w));
#pragma unroll
  for (int i = 1; i < 20; i++) {
    float4 v = p[i];
    m = fmaxf(m, fmaxf(fmaxf(v.x, v.y), fmaxf(v.z, v.w)));
  }

  // pass B: reload + exp accumulate, original op order
  float r8[8];
#pragma unroll
  for (int j = 0; j < 8; j++) r8[j] = 0.0f;
#pragma unroll
  for (int i = 0; i < 10; i++) {
    float4 a = p[2 * i], b = p[2 * i + 1];
    r8[0] += expf(a.x - m); r8[1] += expf(a.y - m);
    r8[2] += expf(a.z - m); r8[3] += expf(a.w - m);
    r8[4] += expf(b.x - m); r8[5] += expf(b.y - m);
    r8[6] += expf(b.z - m); r8[7] += expf(b.w - m);
  }
  float s = ((r8[0] + r8[1]) + (r8[2] + r8[3])) + ((r8[4] + r8[5]) + (r8[6] + r8[7]));
  float sc = 1.0f / s;
  scores[r] = sc;
  if (sc >= 0.05f) {
    int b = r / N;
    uint32_t key = (__float_as_uint(sc) >> 12) - BASEKEY;
    atomicAdd(&ghist[b * NBINS + key], 1u);
  }
}

// ---------------- Kernel 2: per-batch threshold bin (suffix count <= CAP) ----------------
__global__ __launch_bounds__(256)
void thresh_kernel(const uint32_t* __restrict__ ghist, uint32_t* __restrict__ Tb) {
  __shared__ uint32_t chs[256];
  const int b = blockIdx.x;
  const int tid = threadIdx.x;
  const uint32_t* h = ghist + b * NBINS;
  uint32_t csum = 0;
#pragma unroll
  for (int j = 0; j < CHUNKB; j++) csum += h[tid * CHUNKB + j];
  chs[tid] = csum;
  __syncthreads();
  for (int off = 1; off < 256; off <<= 1) {
    uint32_t v = chs[tid];
    uint32_t add = (tid + off < 256) ? chs[tid + off] : 0u;
    __syncthreads();
    chs[tid] = v + add;
    __syncthreads();
  }
  uint32_t St = chs[tid];
  uint32_t Sprev = (tid > 0) ? chs[tid - 1] : 0xFFFFFFFFu;
  if (St <= CAP && (tid == 0 || Sprev > CAP)) {
    int T = 0;
    if (tid != 0) {
      uint32_t cum = St;
      int lo = (tid - 1) * CHUNKB;
      T = lo;
      for (int bb = tid * CHUNKB - 1; bb >= lo; bb--) {
        uint32_t nb = cum + h[bb];
        if (nb > CAP) { T = bb + 1; break; }
        cum = nb;
        if (bb == lo) T = lo;
      }
    }
    Tb[b] = (uint32_t)T;
  }
}

// ---------------- Kernel 3: hierarchical compact (1 atomic per block) ----------------
__global__ __launch_bounds__(1024)
void compact_kernel(const float* __restrict__ scores,
                    const uint32_t* __restrict__ Tb,
                    uint32_t* __restrict__ ctr,
                    uint32_t* __restrict__ csb, uint32_t* __restrict__ cidx,
                    int N) {
  __shared__ uint32_t wbase[16];
  __shared__ uint32_t blkbase;
  const int b = blockIdx.y;
  const int i = blockIdx.x * 1024 + threadIdx.x;
  const int lane = threadIdx.x & 63, wid = threadIdx.x >> 6;

  bool q = false;
  float s = 0.f;
  if (i < N) {
    s = scores[(size_t)b * N + i];
    if (s >= 0.05f) {
      uint32_t key = (__float_as_uint(s) >> 12) - BASEKEY;
      q = key >= Tb[b];
    }
  }
  unsigned long long mask = __ballot(q);
  uint32_t wcnt = (uint32_t)__popcll(mask);
  uint32_t lpre = (uint32_t)__popcll(mask & ((1ULL << lane) - 1ULL));
  if (lane == 0) wbase[wid] = wcnt;
  __syncthreads();
  if (threadIdx.x == 0) {
    uint32_t tot = 0;
#pragma unroll
    for (int w = 0; w < 16; w++) { uint32_t c = wbase[w]; wbase[w] = tot; tot += c; }
    blkbase = tot ? atomicAdd(&ctr[b], tot) : 0u;
  }
  __syncthreads();
  if (q) {
    uint32_t slot = blkbase + wbase[wid] + lpre;
    if (slot < CAP) {
      csb[b * CAP + slot] = __float_as_uint(s);
      cidx[b * CAP + slot] = (uint32_t)i;
    }
  }
}

// ---------------- Kernel 4: sort + accepted-list greedy NMS ----------------
__global__ __launch_bounds__(256, 1)
void nms_kernel(const float* __restrict__ box,
                const uint32_t* __restrict__ csb, const uint32_t* __restrict__ cidx,
                const uint32_t* __restrict__ ctr,
                uint32_t* __restrict__ pick_idx, uint32_t* __restrict__ pick_ok, int N) {
  __shared__ unsigned long long sk[CAP];
  __shared__ float sbox[CAP][4];
  __shared__ uint32_t sidx[CAP];
  __shared__ float accb[MAXDET][4];

  const int b = blockIdx.x;
  const int tid = threadIdx.x;
  uint32_t nc = ctr[b]; if (nc > CAP) nc = CAP;

#pragma unroll
  for (int q = 0; q < CAP / 256; q++) {
    int s = tid + q * 256;
    unsigned long long k = 0ULL;
    if (s < (int)nc)
      k = ((unsigned long long)csb[b * CAP + s] << 32) |
          (unsigned long long)(cidx[b * CAP + s] ^ 0xFFFFFFFFu);
    sk[s] = k;
  }
  __syncthreads();

  // bitonic sort, descending
  for (int k = 2; k <= CAP; k <<= 1) {
    for (int j = k >> 1; j > 0; j >>= 1) {
#pragma unroll
      for (int q = 0; q < CAP / 256; q++) {
        int i = tid + q * 256;
        int ixj = i ^ j;
        if (ixj > i) {
          unsigned long long a = sk[i], c = sk[ixj];
          if (((i & k) == 0) ? (a < c) : (a > c)) { sk[i] = c; sk[ixj] = a; }
        }
      }
      __syncthreads();
    }
  }

  // gather boxes of sorted candidates into LDS (corner-interp xywh form)
#pragma unroll
  for (int q = 0; q < CAP / 256; q++) {
    int s = tid + q * 256;
    unsigned long long k = sk[s];
    uint32_t idx = (uint32_t)k ^ 0xFFFFFFFFu;
    sidx[s] = idx;
    if (k != 0ULL) {
      const float4 f = *(const float4*)(box + ((size_t)b * N + idx) * 4);
      sbox[s][0] = f.x; sbox[s][1] = f.y; sbox[s][2] = f.z - f.x; sbox[s][3] = f.w - f.y;
    } else {
      sbox[s][0] = 0.f; sbox[s][1] = 0.f; sbox[s][2] = 0.f; sbox[s][3] = 0.f;
    }
  }
  __syncthreads();
  if (tid >= 64) return;   // walk is wave0-only; no barriers below

  const int lane = tid;
  uint32_t* pidx = pick_idx + b * MAXDET;
  uint32_t* pok  = pick_ok  + b * MAXDET;

  int nacc = 0;
  for (int cursor = 0; cursor < (int)nc && nacc < MAXDET; cursor += 64) {
    const int c = cursor + lane;
    bool alive = (c < (int)nc);
    float c0 = 0.f, c1 = 0.f, c2 = 0.f, c3 = 0.f;
    uint32_t myidx = 0;
    if (alive) {
      c0 = sbox[c][0]; c1 = sbox[c][1]; c2 = sbox[c][2]; c3 = sbox[c][3];
      myidx = sidx[c];
    }
    const float area_b = (c2 - c0) * (c3 - c1);

    for (int a = 0; a < nacc; a++) {
      float a_r = accb[a][0], b_r = accb[a][1], cc_r = accb[a][2], d_r = accb[a][3];
      float area_r = (cc_r - a_r) * (d_r - b_r);
      float ih = fmaxf(0.f, fminf(cc_r, c2) - fmaxf(a_r, c0));
      float iw = fmaxf(0.f, fminf(d_r, c3) - fmaxf(b_r, c1));
      float inter = ih * iw;
      float uni = area_r + area_b - inter;
      bool okk = (area_r > 0.f) && (area_b > 0.f) && (uni > 0.f);
      float iou = okk ? (inter / uni) : 0.f;
      if (iou > 0.5f) alive = false;
    }

    unsigned long long am = __ballot(alive);
    while (am != 0ULL && nacc < MAXDET) {
      int L = (int)(__ffsll(am) - 1);
      float r0 = __shfl(c0, L), r1 = __shfl(c1, L);
      float r2 = __shfl(c2, L), r3 = __shfl(c3, L);
      uint32_t ridx = (uint32_t)__shfl((int)myidx, L);
      if (lane == 0) {
        pidx[nacc] = ridx; pok[nacc] = 1;
        accb[nacc][0] = r0; accb[nacc][1] = r1;
        accb[nacc][2] = r2; accb[nacc][3] = r3;
      }
      asm volatile("s_waitcnt lgkmcnt(0)" ::: "memory");
      if (lane == L) alive = false;
      if (alive) {
        float area_r = (r2 - r0) * (r3 - r1);
        float ih = fmaxf(0.f, fminf(r2, c2) - fmaxf(r0, c0));
        float iw = fmaxf(0.f, fminf(r3, c3) - fmaxf(r1, c1));
        float inter = ih * iw;
        float uni = area_r + area_b - inter;
        bool okk = (area_r > 0.f) && (area_b > 0.f) && (uni > 0.f);
        float iou = okk ? (inter / uni) : 0.f;
        if (iou > 0.5f) alive = false;
      }
      am = __ballot(alive);
      nacc++;
    }
  }

  if (lane == 0)
    for (int mm = nacc; mm < MAXDET; mm++) { pidx[mm] = 0; pok[mm] = 0; }
}

// ---------------- Kernel 5: gather outputs ----------------
__global__ void out_kernel(const float* __restrict__ box, const float* __restrict__ cls,
                           const uint32_t* __restrict__ pidx, const uint32_t* __restrict__ pok,
                           float* __restrict__ out, int N) {
  int r = blockIdx.x * blockDim.x + threadIdx.x;
  if (r >= BATCH * MAXDET) return;
  int b = r / MAXDET;
  float* boxes_out  = out;
  float* clsidx_out = out + BATCH * MAXDET * 4;
  float* cls_out    = out + BATCH * MAXDET * 4 + BATCH * MAXDET;

  uint32_t ok = pok[r];
  uint32_t idx = pidx[r];
  if (!ok) {
    boxes_out[r * 4 + 0] = 0.f; boxes_out[r * 4 + 1] = 0.f;
    boxes_out[r * 4 + 2] = 0.f; boxes_out[r * 4 + 3] = 0.f;
    clsidx_out[r] = 0.f;
    for (int j = 0; j < NCLS; j++) cls_out[r * NCLS + j] = 0.f;
    return;
  }
  const float4 f = *(const float4*)(box + ((size_t)b * N + idx) * 4);
  boxes_out[r * 4 + 0] = f.x;
  boxes_out[r * 4 + 1] = f.y;
  boxes_out[r * 4 + 2] = f.z - f.x;
  boxes_out[r * 4 + 3] = f.w - f.y;

  const float4* p = (const float4*)(cls + ((size_t)b * N + idx) * NCLS);
  float x[NCLS];
#pragma unroll
  for (int i = 0; i < NCLS / 4; i++) {
    float4 v = p[i];
    x[4 * i] = v.x; x[4 * i + 1] = v.y; x[4 * i + 2] = v.z; x[4 * i + 3] = v.w;
  }
  float m = x[0];
#pragma unroll
  for (int i = 1; i < NCLS; i++) m = fmaxf(m, x[i]);
  float e[NCLS];
#pragma unroll
  for (int i = 0; i < NCLS; i++) e[i] = expf(x[i] - m);
  float r8[8];
#pragma unroll
  for (int j = 0; j < 8; j++) r8[j] = 0.0f;
#pragma unroll
  for (int i = 0; i < NCLS / 8; i++)
#pragma unroll
    for (int j = 0; j < 8; j++) r8[j] += e[i * 8 + j];
  float s = ((r8[0] + r8[1]) + (r8[2] + r8[3])) + ((r8[4] + r8[5]) + (r8[6] + r8[7]));

  float best = -1.f; int bi = 0;
  for (int j = 0; j < NCLS; j++) {
    float pj = e[j] / s;
    cls_out[r * NCLS + j] = pj;
    if (pj > best) { best = pj; bi = j; }
  }
  clsidx_out[r] = (float)bi;
}

extern "C" void kernel_launch(void* const* d_in, const int* in_sizes, int n_in,
                              void* d_out, int out_size, void* d_ws, size_t ws_size,
                              hipStream_t stream) {
  (void)n_in; (void)out_size; (void)ws_size;
  const float* box = (const float*)d_in[0];
  const float* cls = (const float*)d_in[1];
  const int N = in_sizes[0] / (BATCH * 4);
  const int BN = BATCH * N;

  float*    ws_scores = (float*)d_ws;                          // BN floats
  uint32_t* ghist = (uint32_t*)(ws_scores + (size_t)BN);       // BATCH*NBINS
  uint32_t* ctr   = ghist + BATCH * NBINS;                     // BATCH
  uint32_t* Tb    = ctr + BATCH;                               // BATCH
  uint32_t* csb   = Tb + BATCH;                                // BATCH*CAP
  uint32_t* cidx  = csb + BATCH * CAP;                         // BATCH*CAP
  uint32_t* pidx  = cidx + BATCH * CAP;                        // BATCH*MAXDET
  uint32_t* pok   = pidx + BATCH * MAXDET;                     // BATCH*MAXDET

  zero_kernel<<<(BATCH * NBINS + 255) / 256, 256, 0, stream>>>(ghist, ctr, Tb);
  scores_kernel<<<(BN + 255) / 256, 256, 0, stream>>>(cls, ws_scores, ghist, N, BN);
  thresh_kernel<<<BATCH, 256, 0, stream>>>(ghist, Tb);
  dim3 cgrid((N + 1023) / 1024, BATCH);
  compact_kernel<<<cgrid, 1024, 0, stream>>>(ws_scores, Tb, ctr, csb, cidx, N);
  nms_kernel<<<BATCH, 256, 0, stream>>>(box, csb, cidx, ctr, pidx, pok, N);
  out_kernel<<<(BATCH * MAXDET + 255) / 256, 256, 0, stream>>>(box, cls, pidx, pok,
                                                               (float*)d_out, N);
}

// Round 8
// 174.389 us; speedup vs baseline: 1.3404x; 1.3404x over previous
//
#include <hip/hip_runtime.h>
#include <stdint.h>

#define BATCH 8
#define NCLS 80
#define MAXDET 100
#define CAP 1024
#define NBINS 10240          // keys 0..10036 (score 1.0) fit without clamping
#define CHUNKB 40            // 256 threads * 40 bins = 10240
#define BASEKEY (0x3D4CCCCDu >> 12)   // float bits of 0.05f >> 12

// ---------------- Kernel 0: zero per-call state ----------------
__global__ void zero_kernel(uint32_t* __restrict__ ghist, uint32_t* __restrict__ ctr,
                            uint32_t* __restrict__ Tb) {
  int i = blockIdx.x * blockDim.x + threadIdx.x;
  if (i < BATCH * NBINS) ghist[i] = 0;
  if (i < BATCH) { ctr[i] = 0; Tb[i] = NBINS; }
}

// ---------------- Kernel 1: scores, 4 lanes per row, bit-exact ----------------
// lane l of each 4-lane group holds elements x[8i+2l], x[8i+2l+1] (10 float2s).
// Max: per-lane fmax + shfl_xor tree (fmax exactly assoc/comm).
// Sum: lane l accumulates r8[2l], r8[2l+1] in exact i-order; the shfl tree
// reproduces ((r8[0]+r8[1])+(r8[2]+r8[3]))+((r8[4]+r8[5])+(r8[6]+r8[7]))
// bit-exactly. 32 B contiguous per 4-lane group per instr -> good coalescing.
__global__ __launch_bounds__(256)
void scores_kernel(const float* __restrict__ cls,
                   float* __restrict__ scores,
                   uint32_t* __restrict__ ghist, int N, int BN) {
  int gid = blockIdx.x * 256 + threadIdx.x;
  int row = gid >> 2;
  int l = gid & 3;
  if (row >= BN) return;
  const float2* p = (const float2*)(cls + (size_t)row * NCLS);

  float2 v[10];
#pragma unroll
  for (int i = 0; i < 10; i++) v[i] = p[l + 4 * i];

  float m = fmaxf(v[0].x, v[0].y);
#pragma unroll
  for (int i = 1; i < 10; i++) m = fmaxf(m, fmaxf(v[i].x, v[i].y));
  m = fmaxf(m, __shfl_xor(m, 1));
  m = fmaxf(m, __shfl_xor(m, 2));

  float a0 = 0.f, a1 = 0.f;
#pragma unroll
  for (int i = 0; i < 10; i++) {
    a0 += expf(v[i].x - m);
    a1 += expf(v[i].y - m);
  }
  float pr = a0 + a1;                       // r8[2l] + r8[2l+1]
  float u = pr + __shfl_xor(pr, 1);         // (01)+(23) | (45)+(67)
  float s = u + __shfl_xor(u, 2);           // ((01)+(23)) + ((45)+(67))
  float sc = 1.0f / s;

  if (l == 0) {
    scores[row] = sc;
    if (sc >= 0.05f) {
      int b = row / N;
      uint32_t key = (__float_as_uint(sc) >> 12) - BASEKEY;
      atomicAdd(&ghist[b * NBINS + key], 1u);
    }
  }
}

// ---------------- Kernel 2: per-batch threshold bin (suffix count <= CAP) ----------------
__global__ __launch_bounds__(256)
void thresh_kernel(const uint32_t* __restrict__ ghist, uint32_t* __restrict__ Tb) {
  __shared__ uint32_t chs[256];
  const int b = blockIdx.x;
  const int tid = threadIdx.x;
  const uint32_t* h = ghist + b * NBINS;
  uint32_t csum = 0;
#pragma unroll
  for (int j = 0; j < CHUNKB; j++) csum += h[tid * CHUNKB + j];
  chs[tid] = csum;
  __syncthreads();
  for (int off = 1; off < 256; off <<= 1) {
    uint32_t v = chs[tid];
    uint32_t add = (tid + off < 256) ? chs[tid + off] : 0u;
    __syncthreads();
    chs[tid] = v + add;
    __syncthreads();
  }
  uint32_t St = chs[tid];
  uint32_t Sprev = (tid > 0) ? chs[tid - 1] : 0xFFFFFFFFu;
  if (St <= CAP && (tid == 0 || Sprev > CAP)) {
    int T = 0;
    if (tid != 0) {
      uint32_t cum = St;
      int lo = (tid - 1) * CHUNKB;
      T = lo;
      for (int bb = tid * CHUNKB - 1; bb >= lo; bb--) {
        uint32_t nb = cum + h[bb];
        if (nb > CAP) { T = bb + 1; break; }
        cum = nb;
        if (bb == lo) T = lo;
      }
    }
    Tb[b] = (uint32_t)T;
  }
}

// ---------------- Kernel 3: hierarchical compact (1 atomic per block) ----------------
__global__ __launch_bounds__(1024)
void compact_kernel(const float* __restrict__ scores,
                    const uint32_t* __restrict__ Tb,
                    uint32_t* __restrict__ ctr,
                    uint32_t* __restrict__ csb, uint32_t* __restrict__ cidx,
                    int N) {
  __shared__ uint32_t wbase[16];
  __shared__ uint32_t blkbase;
  const int b = blockIdx.y;
  const int i = blockIdx.x * 1024 + threadIdx.x;
  const int lane = threadIdx.x & 63, wid = threadIdx.x >> 6;

  bool q = false;
  float s = 0.f;
  if (i < N) {
    s = scores[(size_t)b * N + i];
    if (s >= 0.05f) {
      uint32_t key = (__float_as_uint(s) >> 12) - BASEKEY;
      q = key >= Tb[b];
    }
  }
  unsigned long long mask = __ballot(q);
  uint32_t wcnt = (uint32_t)__popcll(mask);
  uint32_t lpre = (uint32_t)__popcll(mask & ((1ULL << lane) - 1ULL));
  if (lane == 0) wbase[wid] = wcnt;
  __syncthreads();
  if (threadIdx.x == 0) {
    uint32_t tot = 0;
#pragma unroll
    for (int w = 0; w < 16; w++) { uint32_t c = wbase[w]; wbase[w] = tot; tot += c; }
    blkbase = tot ? atomicAdd(&ctr[b], tot) : 0u;
  }
  __syncthreads();
  if (q) {
    uint32_t slot = blkbase + wbase[wid] + lpre;
    if (slot < CAP) {
      csb[b * CAP + slot] = __float_as_uint(s);
      cidx[b * CAP + slot] = (uint32_t)i;
    }
  }
}

// ---------------- Kernel 4: sort + accepted-list greedy NMS ----------------
__global__ __launch_bounds__(256, 1)
void nms_kernel(const float* __restrict__ box,
                const uint32_t* __restrict__ csb, const uint32_t* __restrict__ cidx,
                const uint32_t* __restrict__ ctr,
                uint32_t* __restrict__ pick_idx, uint32_t* __restrict__ pick_ok, int N) {
  __shared__ unsigned long long sk[CAP];
  __shared__ float sbox[CAP][4];
  __shared__ uint32_t sidx[CAP];
  __shared__ float accb[MAXDET][4];

  const int b = blockIdx.x;
  const int tid = threadIdx.x;
  uint32_t nc = ctr[b]; if (nc > CAP) nc = CAP;

#pragma unroll
  for (int q = 0; q < CAP / 256; q++) {
    int s = tid + q * 256;
    unsigned long long k = 0ULL;
    if (s < (int)nc)
      k = ((unsigned long long)csb[b * CAP + s] << 32) |
          (unsigned long long)(cidx[b * CAP + s] ^ 0xFFFFFFFFu);
    sk[s] = k;
  }
  __syncthreads();

  // bitonic sort, descending
  for (int k = 2; k <= CAP; k <<= 1) {
    for (int j = k >> 1; j > 0; j >>= 1) {
#pragma unroll
      for (int q = 0; q < CAP / 256; q++) {
        int i = tid + q * 256;
        int ixj = i ^ j;
        if (ixj > i) {
          unsigned long long a = sk[i], c = sk[ixj];
          if (((i & k) == 0) ? (a < c) : (a > c)) { sk[i] = c; sk[ixj] = a; }
        }
      }
      __syncthreads();
    }
  }

  // gather boxes of sorted candidates into LDS (corner-interp xywh form)
#pragma unroll
  for (int q = 0; q < CAP / 256; q++) {
    int s = tid + q * 256;
    unsigned long long k = sk[s];
    uint32_t idx = (uint32_t)k ^ 0xFFFFFFFFu;
    sidx[s] = idx;
    if (k != 0ULL) {
      const float4 f = *(const float4*)(box + ((size_t)b * N + idx) * 4);
      sbox[s][0] = f.x; sbox[s][1] = f.y; sbox[s][2] = f.z - f.x; sbox[s][3] = f.w - f.y;
    } else {
      sbox[s][0] = 0.f; sbox[s][1] = 0.f; sbox[s][2] = 0.f; sbox[s][3] = 0.f;
    }
  }
  __syncthreads();
  if (tid >= 64) return;   // walk is wave0-only; no barriers below

  const int lane = tid;
  uint32_t* pidx = pick_idx + b * MAXDET;
  uint32_t* pok  = pick_ok  + b * MAXDET;

  int nacc = 0;
  for (int cursor = 0; cursor < (int)nc && nacc < MAXDET; cursor += 64) {
    const int c = cursor + lane;
    bool alive = (c < (int)nc);
    float c0 = 0.f, c1 = 0.f, c2 = 0.f, c3 = 0.f;
    uint32_t myidx = 0;
    if (alive) {
      c0 = sbox[c][0]; c1 = sbox[c][1]; c2 = sbox[c][2]; c3 = sbox[c][3];
      myidx = sidx[c];
    }
    const float area_b = (c2 - c0) * (c3 - c1);

    for (int a = 0; a < nacc; a++) {
      float a_r = accb[a][0], b_r = accb[a][1], cc_r = accb[a][2], d_r = accb[a][3];
      float area_r = (cc_r - a_r) * (d_r - b_r);
      float ih = fmaxf(0.f, fminf(cc_r, c2) - fmaxf(a_r, c0));
      float iw = fmaxf(0.f, fminf(d_r, c3) - fmaxf(b_r, c1));
      float inter = ih * iw;
      float uni = area_r + area_b - inter;
      bool okk = (area_r > 0.f) && (area_b > 0.f) && (uni > 0.f);
      float iou = okk ? (inter / uni) : 0.f;
      if (iou > 0.5f) alive = false;
    }

    unsigned long long am = __ballot(alive);
    while (am != 0ULL && nacc < MAXDET) {
      int L = (int)(__ffsll(am) - 1);
      float r0 = __shfl(c0, L), r1 = __shfl(c1, L);
      float r2 = __shfl(c2, L), r3 = __shfl(c3, L);
      uint32_t ridx = (uint32_t)__shfl((int)myidx, L);
      if (lane == 0) {
        pidx[nacc] = ridx; pok[nacc] = 1;
        accb[nacc][0] = r0; accb[nacc][1] = r1;
        accb[nacc][2] = r2; accb[nacc][3] = r3;
      }
      asm volatile("s_waitcnt lgkmcnt(0)" ::: "memory");
      if (lane == L) alive = false;
      if (alive) {
        float area_r = (r2 - r0) * (r3 - r1);
        float ih = fmaxf(0.f, fminf(r2, c2) - fmaxf(r0, c0));
        float iw = fmaxf(0.f, fminf(r3, c3) - fmaxf(r1, c1));
        float inter = ih * iw;
        float uni = area_r + area_b - inter;
        bool okk = (area_r > 0.f) && (area_b > 0.f) && (uni > 0.f);
        float iou = okk ? (inter / uni) : 0.f;
        if (iou > 0.5f) alive = false;
      }
      am = __ballot(alive);
      nacc++;
    }
  }

  if (lane == 0)
    for (int mm = nacc; mm < MAXDET; mm++) { pidx[mm] = 0; pok[mm] = 0; }
}

// ---------------- Kernel 5: gather outputs ----------------
__global__ void out_kernel(const float* __restrict__ box, const float* __restrict__ cls,
                           const uint32_t* __restrict__ pidx, const uint32_t* __restrict__ pok,
                           float* __restrict__ out, int N) {
  int r = blockIdx.x * blockDim.x + threadIdx.x;
  if (r >= BATCH * MAXDET) return;
  int b = r / MAXDET;
  float* boxes_out  = out;
  float* clsidx_out = out + BATCH * MAXDET * 4;
  float* cls_out    = out + BATCH * MAXDET * 4 + BATCH * MAXDET;

  uint32_t ok = pok[r];
  uint32_t idx = pidx[r];
  if (!ok) {
    boxes_out[r * 4 + 0] = 0.f; boxes_out[r * 4 + 1] = 0.f;
    boxes_out[r * 4 + 2] = 0.f; boxes_out[r * 4 + 3] = 0.f;
    clsidx_out[r] = 0.f;
    for (int j = 0; j < NCLS; j++) cls_out[r * NCLS + j] = 0.f;
    return;
  }
  const float4 f = *(const float4*)(box + ((size_t)b * N + idx) * 4);
  boxes_out[r * 4 + 0] = f.x;
  boxes_out[r * 4 + 1] = f.y;
  boxes_out[r * 4 + 2] = f.z - f.x;
  boxes_out[r * 4 + 3] = f.w - f.y;

  const float4* p = (const float4*)(cls + ((size_t)b * N + idx) * NCLS);
  float x[NCLS];
#pragma unroll
  for (int i = 0; i < NCLS / 4; i++) {
    float4 v = p[i];
    x[4 * i] = v.x; x[4 * i + 1] = v.y; x[4 * i + 2] = v.z; x[4 * i + 3] = v.w;
  }
  float m = x[0];
#pragma unroll
  for (int i = 1; i < NCLS; i++) m = fmaxf(m, x[i]);
  float e[NCLS];
#pragma unroll
  for (int i = 0; i < NCLS; i++) e[i] = expf(x[i] - m);
  float r8[8];
#pragma unroll
  for (int j = 0; j < 8; j++) r8[j] = 0.0f;
#pragma unroll
  for (int i = 0; i < NCLS / 8; i++)
#pragma unroll
    for (int j = 0; j < 8; j++) r8[j] += e[i * 8 + j];
  float s = ((r8[0] + r8[1]) + (r8[2] + r8[3])) + ((r8[4] + r8[5]) + (r8[6] + r8[7]));

  float best = -1.f; int bi = 0;
  for (int j = 0; j < NCLS; j++) {
    float pj = e[j] / s;
    cls_out[r * NCLS + j] = pj;
    if (pj > best) { best = pj; bi = j; }
  }
  clsidx_out[r] = (float)bi;
}

extern "C" void kernel_launch(void* const* d_in, const int* in_sizes, int n_in,
                              void* d_out, int out_size, void* d_ws, size_t ws_size,
                              hipStream_t stream) {
  (void)n_in; (void)out_size; (void)ws_size;
  const float* box = (const float*)d_in[0];
  const float* cls = (const float*)d_in[1];
  const int N = in_sizes[0] / (BATCH * 4);
  const int BN = BATCH * N;

  float*    ws_scores = (float*)d_ws;                          // BN floats
  uint32_t* ghist = (uint32_t*)(ws_scores + (size_t)BN);       // BATCH*NBINS
  uint32_t* ctr   = ghist + BATCH * NBINS;                     // BATCH
  uint32_t* Tb    = ctr + BATCH;                               // BATCH
  uint32_t* csb   = Tb + BATCH;                                // BATCH*CAP
  uint32_t* cidx  = csb + BATCH * CAP;                         // BATCH*CAP
  uint32_t* pidx  = cidx + BATCH * CAP;                        // BATCH*MAXDET
  uint32_t* pok   = pidx + BATCH * MAXDET;                     // BATCH*MAXDET

  zero_kernel<<<(BATCH * NBINS + 255) / 256, 256, 0, stream>>>(ghist, ctr, Tb);
  {
    long long tot = (long long)BN * 4;
    int blocks = (int)((tot + 255) / 256);
    scores_kernel<<<blocks, 256, 0, stream>>>(cls, ws_scores, ghist, N, BN);
  }
  thresh_kernel<<<BATCH, 256, 0, stream>>>(ghist, Tb);
  dim3 cgrid((N + 1023) / 1024, BATCH);
  compact_kernel<<<cgrid, 1024, 0, stream>>>(ws_scores, Tb, ctr, csb, cidx, N);
  nms_kernel<<<BATCH, 256, 0, stream>>>(box, csb, cidx, ctr, pidx, pok, N);
  out_kernel<<<(BATCH * MAXDET + 255) / 256, 256, 0, stream>>>(box, cls, pidx, pok,
                                                               (float*)d_out, N);
}

// Round 9
// 158.082 us; speedup vs baseline: 1.4787x; 1.1032x over previous
//
#include <hip/hip_runtime.h>
#include <stdint.h>

#define BATCH 8
#define NCLS 80
#define MAXDET 100
#define CAP 512
#define NBINS 10240          // keys 0..10036 (score 1.0) fit without clamping
#define CHUNKB 40            // 256 threads * 40 bins = 10240
#define BASEKEY (0x3D4CCCCDu >> 12)   // float bits of 0.05f >> 12

// ---------------- Kernel 0: zero per-call state ----------------
__global__ void zero_kernel(uint32_t* __restrict__ ghist, uint32_t* __restrict__ ctr,
                            uint32_t* __restrict__ Tb) {
  int i = blockIdx.x * blockDim.x + threadIdx.x;
  if (i < BATCH * NBINS) ghist[i] = 0;
  if (i < BATCH) { ctr[i] = 0; Tb[i] = NBINS; }
}

// ---------------- Kernel 1: scores, 2 lanes per row, float4 loads, bit-exact ----
// lane l in {0,1} loads p4[l+2i] = x[8i+4l .. 8i+4l+3], i=0..9.
// a[j] += expf(x - m) in ascending-i order == r8[4l+j] exactly.
// s_half = (a0+a1)+(a2+a3); s = s_half + shfl_xor(s_half,1) == reference sum
// bit-exactly (IEEE add commutative). fmax tree exact for max.
__global__ __launch_bounds__(256)
void scores_kernel(const float* __restrict__ cls,
                   float* __restrict__ scores,
                   uint32_t* __restrict__ ghist, int N, int BN) {
  int gid = blockIdx.x * 256 + threadIdx.x;
  int row = gid >> 1;
  int l = gid & 1;
  if (row >= BN) return;
  const float4* p4 = (const float4*)(cls + (size_t)row * NCLS);

  float4 v[10];
#pragma unroll
  for (int i = 0; i < 10; i++) v[i] = p4[l + 2 * i];

  float m = fmaxf(fmaxf(v[0].x, v[0].y), fmaxf(v[0].z, v[0].w));
#pragma unroll
  for (int i = 1; i < 10; i++)
    m = fmaxf(m, fmaxf(fmaxf(v[i].x, v[i].y), fmaxf(v[i].z, v[i].w)));
  m = fmaxf(m, __shfl_xor(m, 1));

  float a0 = 0.f, a1 = 0.f, a2 = 0.f, a3 = 0.f;
#pragma unroll
  for (int i = 0; i < 10; i++) {
    a0 += expf(v[i].x - m);
    a1 += expf(v[i].y - m);
    a2 += expf(v[i].z - m);
    a3 += expf(v[i].w - m);
  }
  float s_half = (a0 + a1) + (a2 + a3);      // (r8[4l]+r8[4l+1])+(r8[4l+2]+r8[4l+3])
  float s = s_half + __shfl_xor(s_half, 1);  // half0 + half1
  float sc = 1.0f / s;

  if (l == 0) {
    scores[row] = sc;
    if (sc >= 0.05f) {
      int b = row / N;
      uint32_t key = (__float_as_uint(sc) >> 12) - BASEKEY;
      atomicAdd(&ghist[b * NBINS + key], 1u);
    }
  }
}

// ---------------- Kernel 2: per-batch threshold bin (suffix count <= CAP) ----------------
__global__ __launch_bounds__(256)
void thresh_kernel(const uint32_t* __restrict__ ghist, uint32_t* __restrict__ Tb) {
  __shared__ uint32_t chs[256];
  const int b = blockIdx.x;
  const int tid = threadIdx.x;
  const uint32_t* h = ghist + b * NBINS;
  uint32_t csum = 0;
#pragma unroll
  for (int j = 0; j < CHUNKB; j++) csum += h[tid * CHUNKB + j];
  chs[tid] = csum;
  __syncthreads();
  for (int off = 1; off < 256; off <<= 1) {
    uint32_t v = chs[tid];
    uint32_t add = (tid + off < 256) ? chs[tid + off] : 0u;
    __syncthreads();
    chs[tid] = v + add;
    __syncthreads();
  }
  uint32_t St = chs[tid];
  uint32_t Sprev = (tid > 0) ? chs[tid - 1] : 0xFFFFFFFFu;
  if (St <= CAP && (tid == 0 || Sprev > CAP)) {
    int T = 0;
    if (tid != 0) {
      uint32_t cum = St;
      int lo = (tid - 1) * CHUNKB;
      T = lo;
      for (int bb = tid * CHUNKB - 1; bb >= lo; bb--) {
        uint32_t nb = cum + h[bb];
        if (nb > CAP) { T = bb + 1; break; }
        cum = nb;
        if (bb == lo) T = lo;
      }
    }
    Tb[b] = (uint32_t)T;
  }
}

// ---------------- Kernel 3: hierarchical compact (1 atomic per block) ----------------
__global__ __launch_bounds__(1024)
void compact_kernel(const float* __restrict__ scores,
                    const uint32_t* __restrict__ Tb,
                    uint32_t* __restrict__ ctr,
                    uint32_t* __restrict__ csb, uint32_t* __restrict__ cidx,
                    int N) {
  __shared__ uint32_t wbase[16];
  __shared__ uint32_t blkbase;
  const int b = blockIdx.y;
  const int i = blockIdx.x * 1024 + threadIdx.x;
  const int lane = threadIdx.x & 63, wid = threadIdx.x >> 6;

  bool q = false;
  float s = 0.f;
  if (i < N) {
    s = scores[(size_t)b * N + i];
    if (s >= 0.05f) {
      uint32_t key = (__float_as_uint(s) >> 12) - BASEKEY;
      q = key >= Tb[b];
    }
  }
  unsigned long long mask = __ballot(q);
  uint32_t wcnt = (uint32_t)__popcll(mask);
  uint32_t lpre = (uint32_t)__popcll(mask & ((1ULL << lane) - 1ULL));
  if (lane == 0) wbase[wid] = wcnt;
  __syncthreads();
  if (threadIdx.x == 0) {
    uint32_t tot = 0;
#pragma unroll
    for (int w = 0; w < 16; w++) { uint32_t c = wbase[w]; wbase[w] = tot; tot += c; }
    blkbase = tot ? atomicAdd(&ctr[b], tot) : 0u;
  }
  __syncthreads();
  if (q) {
    uint32_t slot = blkbase + wbase[wid] + lpre;
    if (slot < CAP) {
      csb[b * CAP + slot] = __float_as_uint(s);
      cidx[b * CAP + slot] = (uint32_t)i;
    }
  }
}

// ---------------- Kernel 4: sort + accepted-list greedy NMS ----------------
__global__ __launch_bounds__(256, 1)
void nms_kernel(const float* __restrict__ box,
                const uint32_t* __restrict__ csb, const uint32_t* __restrict__ cidx,
                const uint32_t* __restrict__ ctr,
                uint32_t* __restrict__ pick_idx, uint32_t* __restrict__ pick_ok, int N) {
  __shared__ unsigned long long sk[CAP];
  __shared__ float sbox[CAP][4];
  __shared__ uint32_t sidx[CAP];
  __shared__ float4 accb[MAXDET];

  const int b = blockIdx.x;
  const int tid = threadIdx.x;
  uint32_t nc = ctr[b]; if (nc > CAP) nc = CAP;

#pragma unroll
  for (int q = 0; q < CAP / 256; q++) {
    int s = tid + q * 256;
    unsigned long long k = 0ULL;
    if (s < (int)nc)
      k = ((unsigned long long)csb[b * CAP + s] << 32) |
          (unsigned long long)(cidx[b * CAP + s] ^ 0xFFFFFFFFu);
    sk[s] = k;
  }
  __syncthreads();

  // bitonic sort, descending
  for (int k = 2; k <= CAP; k <<= 1) {
    for (int j = k >> 1; j > 0; j >>= 1) {
#pragma unroll
      for (int q = 0; q < CAP / 256; q++) {
        int i = tid + q * 256;
        int ixj = i ^ j;
        if (ixj > i) {
          unsigned long long a = sk[i], c = sk[ixj];
          if (((i & k) == 0) ? (a < c) : (a > c)) { sk[i] = c; sk[ixj] = a; }
        }
      }
      __syncthreads();
    }
  }

  // gather boxes of sorted candidates into LDS (corner-interp xywh form)
#pragma unroll
  for (int q = 0; q < CAP / 256; q++) {
    int s = tid + q * 256;
    unsigned long long k = sk[s];
    uint32_t idx = (uint32_t)k ^ 0xFFFFFFFFu;
    sidx[s] = idx;
    if (k != 0ULL) {
      const float4 f = *(const float4*)(box + ((size_t)b * N + idx) * 4);
      sbox[s][0] = f.x; sbox[s][1] = f.y; sbox[s][2] = f.z - f.x; sbox[s][3] = f.w - f.y;
    } else {
      sbox[s][0] = 0.f; sbox[s][1] = 0.f; sbox[s][2] = 0.f; sbox[s][3] = 0.f;
    }
  }
  __syncthreads();
  if (tid >= 64) return;   // walk is wave0-only; no barriers below

  const int lane = tid;
  uint32_t* pidx = pick_idx + b * MAXDET;
  uint32_t* pok  = pick_ok  + b * MAXDET;

  int nacc = 0;
  for (int cursor = 0; cursor < (int)nc && nacc < MAXDET; cursor += 64) {
    const int c = cursor + lane;
    bool alive = (c < (int)nc);
    float c0 = 0.f, c1 = 0.f, c2 = 0.f, c3 = 0.f;
    uint32_t myidx = 0;
    if (alive) {
      c0 = sbox[c][0]; c1 = sbox[c][1]; c2 = sbox[c][2]; c3 = sbox[c][3];
      myidx = sidx[c];
    }
    const float area_b = (c2 - c0) * (c3 - c1);

    // test chunk vs all accepted so far (float4 broadcast reads)
#pragma unroll 2
    for (int a = 0; a < nacc; a++) {
      float4 ar = accb[a];
      float area_r = (ar.z - ar.x) * (ar.w - ar.y);
      float ih = fmaxf(0.f, fminf(ar.z, c2) - fmaxf(ar.x, c0));
      float iw = fmaxf(0.f, fminf(ar.w, c3) - fmaxf(ar.y, c1));
      float inter = ih * iw;
      float uni = area_r + area_b - inter;
      bool okk = (area_r > 0.f) && (area_b > 0.f) && (uni > 0.f);
      float iou = okk ? (inter / uni) : 0.f;
      if (iou > 0.5f) alive = false;
    }

    unsigned long long am = __ballot(alive);
    while (am != 0ULL && nacc < MAXDET) {
      int L = (int)(__ffsll(am) - 1);
      float r0 = __shfl(c0, L), r1 = __shfl(c1, L);
      float r2 = __shfl(c2, L), r3 = __shfl(c3, L);
      uint32_t ridx = (uint32_t)__shfl((int)myidx, L);
      if (lane == 0) {
        pidx[nacc] = ridx; pok[nacc] = 1;
        accb[nacc] = make_float4(r0, r1, r2, r3);
      }
      asm volatile("s_waitcnt lgkmcnt(0)" ::: "memory");
      if (lane == L) alive = false;
      if (alive) {
        float area_r = (r2 - r0) * (r3 - r1);
        float ih = fmaxf(0.f, fminf(r2, c2) - fmaxf(r0, c0));
        float iw = fmaxf(0.f, fminf(r3, c3) - fmaxf(r1, c1));
        float inter = ih * iw;
        float uni = area_r + area_b - inter;
        bool okk = (area_r > 0.f) && (area_b > 0.f) && (uni > 0.f);
        float iou = okk ? (inter / uni) : 0.f;
        if (iou > 0.5f) alive = false;
      }
      am = __ballot(alive);
      nacc++;
    }
  }

  if (lane == 0)
    for (int mm = nacc; mm < MAXDET; mm++) { pidx[mm] = 0; pok[mm] = 0; }
}

// ---------------- Kernel 5: gather outputs ----------------
__global__ void out_kernel(const float* __restrict__ box, const float* __restrict__ cls,
                           const uint32_t* __restrict__ pidx, const uint32_t* __restrict__ pok,
                           float* __restrict__ out, int N) {
  int r = blockIdx.x * blockDim.x + threadIdx.x;
  if (r >= BATCH * MAXDET) return;
  int b = r / MAXDET;
  float* boxes_out  = out;
  float* clsidx_out = out + BATCH * MAXDET * 4;
  float* cls_out    = out + BATCH * MAXDET * 4 + BATCH * MAXDET;

  uint32_t ok = pok[r];
  uint32_t idx = pidx[r];
  if (!ok) {
    boxes_out[r * 4 + 0] = 0.f; boxes_out[r * 4 + 1] = 0.f;
    boxes_out[r * 4 + 2] = 0.f; boxes_out[r * 4 + 3] = 0.f;
    clsidx_out[r] = 0.f;
    for (int j = 0; j < NCLS; j++) cls_out[r * NCLS + j] = 0.f;
    return;
  }
  const float4 f = *(const float4*)(box + ((size_t)b * N + idx) * 4);
  boxes_out[r * 4 + 0] = f.x;
  boxes_out[r * 4 + 1] = f.y;
  boxes_out[r * 4 + 2] = f.z - f.x;
  boxes_out[r * 4 + 3] = f.w - f.y;

  const float4* p = (const float4*)(cls + ((size_t)b * N + idx) * NCLS);
  float x[NCLS];
#pragma unroll
  for (int i = 0; i < NCLS / 4; i++) {
    float4 v = p[i];
    x[4 * i] = v.x; x[4 * i + 1] = v.y; x[4 * i + 2] = v.z; x[4 * i + 3] = v.w;
  }
  float m = x[0];
#pragma unroll
  for (int i = 1; i < NCLS; i++) m = fmaxf(m, x[i]);
  float e[NCLS];
#pragma unroll
  for (int i = 0; i < NCLS; i++) e[i] = expf(x[i] - m);
  float r8[8];
#pragma unroll
  for (int j = 0; j < 8; j++) r8[j] = 0.0f;
#pragma unroll
  for (int i = 0; i < NCLS / 8; i++)
#pragma unroll
    for (int j = 0; j < 8; j++) r8[j] += e[i * 8 + j];
  float s = ((r8[0] + r8[1]) + (r8[2] + r8[3])) + ((r8[4] + r8[5]) + (r8[6] + r8[7]));

  float best = -1.f; int bi = 0;
  for (int j = 0; j < NCLS; j++) {
    float pj = e[j] / s;
    cls_out[r * NCLS + j] = pj;
    if (pj > best) { best = pj; bi = j; }
  }
  clsidx_out[r] = (float)bi;
}

extern "C" void kernel_launch(void* const* d_in, const int* in_sizes, int n_in,
                              void* d_out, int out_size, void* d_ws, size_t ws_size,
                              hipStream_t stream) {
  (void)n_in; (void)out_size; (void)ws_size;
  const float* box = (const float*)d_in[0];
  const float* cls = (const float*)d_in[1];
  const int N = in_sizes[0] / (BATCH * 4);
  const int BN = BATCH * N;

  float*    ws_scores = (float*)d_ws;                          // BN floats
  uint32_t* ghist = (uint32_t*)(ws_scores + (size_t)BN);       // BATCH*NBINS
  uint32_t* ctr   = ghist + BATCH * NBINS;                     // BATCH
  uint32_t* Tb    = ctr + BATCH;                               // BATCH
  uint32_t* csb   = Tb + BATCH;                                // BATCH*CAP
  uint32_t* cidx  = csb + BATCH * CAP;                         // BATCH*CAP
  uint32_t* pidx  = cidx + BATCH * CAP;                        // BATCH*MAXDET
  uint32_t* pok   = pidx + BATCH * MAXDET;                     // BATCH*MAXDET

  zero_kernel<<<(BATCH * NBINS + 255) / 256, 256, 0, stream>>>(ghist, ctr, Tb);
  {
    long long tot = (long long)BN * 2;
    int blocks = (int)((tot + 255) / 256);
    scores_kernel<<<blocks, 256, 0, stream>>>(cls, ws_scores, ghist, N, BN);
  }
  thresh_kernel<<<BATCH, 256, 0, stream>>>(ghist, Tb);
  dim3 cgrid((N + 1023) / 1024, BATCH);
  compact_kernel<<<cgrid, 1024, 0, stream>>>(ws_scores, Tb, ctr, csb, cidx, N);
  nms_kernel<<<BATCH, 256, 0, stream>>>(box, csb, cidx, ctr, pidx, pok, N);
  out_kernel<<<(BATCH * MAXDET + 255) / 256, 256, 0, stream>>>(box, cls, pidx, pok,
                                                               (float*)d_out, N);
}

// Round 10
// 148.200 us; speedup vs baseline: 1.5773x; 1.0667x over previous
//
#include <hip/hip_runtime.h>
#include <stdint.h>

#define BATCH 8
#define NCLS 80
#define MAXDET 100
#define CAP 512
#define NBINS 10240          // keys 0..10036 (score 1.0) fit without clamping
#define HT_THREADS 1024
#define HT_CHUNKB 10         // 1024 threads * 10 bins = 10240
#define BASEKEY (0x3D4CCCCDu >> 12)   // float bits of 0.05f >> 12

// ---------------- Kernel 1: scores, 2 lanes per row, float4 loads, bit-exact ----
// Pure streaming: no histogram, no atomics.
__global__ __launch_bounds__(256)
void scores_kernel(const float* __restrict__ cls,
                   float* __restrict__ scores, int BN) {
  int gid = blockIdx.x * 256 + threadIdx.x;
  int row = gid >> 1;
  int l = gid & 1;
  if (row >= BN) return;
  const float4* p4 = (const float4*)(cls + (size_t)row * NCLS);

  float4 v[10];
#pragma unroll
  for (int i = 0; i < 10; i++) v[i] = p4[l + 2 * i];

  float m = fmaxf(fmaxf(v[0].x, v[0].y), fmaxf(v[0].z, v[0].w));
#pragma unroll
  for (int i = 1; i < 10; i++)
    m = fmaxf(m, fmaxf(fmaxf(v[i].x, v[i].y), fmaxf(v[i].z, v[i].w)));
  m = fmaxf(m, __shfl_xor(m, 1));

  float a0 = 0.f, a1 = 0.f, a2 = 0.f, a3 = 0.f;
#pragma unroll
  for (int i = 0; i < 10; i++) {
    a0 += expf(v[i].x - m);
    a1 += expf(v[i].y - m);
    a2 += expf(v[i].z - m);
    a3 += expf(v[i].w - m);
  }
  float s_half = (a0 + a1) + (a2 + a3);      // (r8[4l]+r8[4l+1])+(r8[4l+2]+r8[4l+3])
  float s = s_half + __shfl_xor(s_half, 1);  // half0 + half1
  if (l == 0) scores[row] = 1.0f / s;
}

// ---------------- Kernel 2: per-batch LDS histogram + threshold ----------------
// One block per batch: LDS histogram of score keys (local atomics only),
// in-block suffix scan -> minimal bin T with suffix-count <= CAP.
// Also zeroes ctr[b] for the compact pass. No global atomics, no pre-zero.
__global__ __launch_bounds__(HT_THREADS)
void histthresh_kernel(const float* __restrict__ scores,
                       uint32_t* __restrict__ Tb, uint32_t* __restrict__ ctr, int N) {
  __shared__ uint32_t lh[NBINS];
  __shared__ uint32_t chs[HT_THREADS];
  const int b = blockIdx.x;
  const int tid = threadIdx.x;

#pragma unroll
  for (int j = 0; j < HT_CHUNKB; j++) lh[tid + j * HT_THREADS] = 0;
  __syncthreads();

  const float* sc = scores + (size_t)b * N;
  for (int i = tid; i < N; i += HT_THREADS) {
    float s = sc[i];
    if (s >= 0.05f) {
      uint32_t key = (__float_as_uint(s) >> 12) - BASEKEY;
      atomicAdd(&lh[key], 1u);
    }
  }
  __syncthreads();

  uint32_t csum = 0;
#pragma unroll
  for (int j = 0; j < HT_CHUNKB; j++) csum += lh[tid * HT_CHUNKB + j];
  chs[tid] = csum;
  __syncthreads();
  for (int off = 1; off < HT_THREADS; off <<= 1) {
    uint32_t v = chs[tid];
    uint32_t add = (tid + off < HT_THREADS) ? chs[tid + off] : 0u;
    __syncthreads();
    chs[tid] = v + add;
    __syncthreads();
  }
  uint32_t St = chs[tid];
  uint32_t Sprev = (tid > 0) ? chs[tid - 1] : 0xFFFFFFFFu;
  if (St <= CAP && (tid == 0 || Sprev > CAP)) {
    int T = 0;
    if (tid != 0) {
      uint32_t cum = St;
      int lo = (tid - 1) * HT_CHUNKB;
      T = lo;
      for (int bb = tid * HT_CHUNKB - 1; bb >= lo; bb--) {
        uint32_t nb = cum + lh[bb];
        if (nb > CAP) { T = bb + 1; break; }
        cum = nb;
        if (bb == lo) T = lo;
      }
    }
    Tb[b] = (uint32_t)T;
  }
  if (tid == 0) ctr[b] = 0;
}

// ---------------- Kernel 3: hierarchical compact (1 atomic per block) ----------------
__global__ __launch_bounds__(1024)
void compact_kernel(const float* __restrict__ scores,
                    const uint32_t* __restrict__ Tb,
                    uint32_t* __restrict__ ctr,
                    uint32_t* __restrict__ csb, uint32_t* __restrict__ cidx,
                    int N) {
  __shared__ uint32_t wbase[16];
  __shared__ uint32_t blkbase;
  const int b = blockIdx.y;
  const int i = blockIdx.x * 1024 + threadIdx.x;
  const int lane = threadIdx.x & 63, wid = threadIdx.x >> 6;

  bool q = false;
  float s = 0.f;
  if (i < N) {
    s = scores[(size_t)b * N + i];
    if (s >= 0.05f) {
      uint32_t key = (__float_as_uint(s) >> 12) - BASEKEY;
      q = key >= Tb[b];
    }
  }
  unsigned long long mask = __ballot(q);
  uint32_t wcnt = (uint32_t)__popcll(mask);
  uint32_t lpre = (uint32_t)__popcll(mask & ((1ULL << lane) - 1ULL));
  if (lane == 0) wbase[wid] = wcnt;
  __syncthreads();
  if (threadIdx.x == 0) {
    uint32_t tot = 0;
#pragma unroll
    for (int w = 0; w < 16; w++) { uint32_t c = wbase[w]; wbase[w] = tot; tot += c; }
    blkbase = tot ? atomicAdd(&ctr[b], tot) : 0u;
  }
  __syncthreads();
  if (q) {
    uint32_t slot = blkbase + wbase[wid] + lpre;
    if (slot < CAP) {
      csb[b * CAP + slot] = __float_as_uint(s);
      cidx[b * CAP + slot] = (uint32_t)i;
    }
  }
}

// ---------------- Kernel 4: sort + accepted-list greedy NMS + fused output ----------------
__global__ __launch_bounds__(256, 1)
void nmsout_kernel(const float* __restrict__ box, const float* __restrict__ cls,
                   const uint32_t* __restrict__ csb, const uint32_t* __restrict__ cidx,
                   const uint32_t* __restrict__ ctr,
                   float* __restrict__ out, int N) {
  __shared__ unsigned long long sk[CAP];
  __shared__ float sbox[CAP][4];
  __shared__ uint32_t sidx[CAP];
  __shared__ float4 accb[MAXDET];
  __shared__ uint32_t pick_i[MAXDET];
  __shared__ int nacc_sh;

  const int b = blockIdx.x;
  const int tid = threadIdx.x;
  uint32_t nc = ctr[b]; if (nc > CAP) nc = CAP;

#pragma unroll
  for (int q = 0; q < CAP / 256; q++) {
    int s = tid + q * 256;
    unsigned long long k = 0ULL;
    if (s < (int)nc)
      k = ((unsigned long long)csb[b * CAP + s] << 32) |
          (unsigned long long)(cidx[b * CAP + s] ^ 0xFFFFFFFFu);
    sk[s] = k;
  }
  __syncthreads();

  // bitonic sort, descending
  for (int k = 2; k <= CAP; k <<= 1) {
    for (int j = k >> 1; j > 0; j >>= 1) {
#pragma unroll
      for (int q = 0; q < CAP / 256; q++) {
        int i = tid + q * 256;
        int ixj = i ^ j;
        if (ixj > i) {
          unsigned long long a = sk[i], c = sk[ixj];
          if (((i & k) == 0) ? (a < c) : (a > c)) { sk[i] = c; sk[ixj] = a; }
        }
      }
      __syncthreads();
    }
  }

  // gather boxes of sorted candidates into LDS (corner-interp xywh form)
#pragma unroll
  for (int q = 0; q < CAP / 256; q++) {
    int s = tid + q * 256;
    unsigned long long k = sk[s];
    uint32_t idx = (uint32_t)k ^ 0xFFFFFFFFu;
    sidx[s] = idx;
    if (k != 0ULL) {
      const float4 f = *(const float4*)(box + ((size_t)b * N + idx) * 4);
      sbox[s][0] = f.x; sbox[s][1] = f.y; sbox[s][2] = f.z - f.x; sbox[s][3] = f.w - f.y;
    } else {
      sbox[s][0] = 0.f; sbox[s][1] = 0.f; sbox[s][2] = 0.f; sbox[s][3] = 0.f;
    }
  }
  __syncthreads();

  if (tid < 64) {   // wave0-only walk, no barriers inside
    const int lane = tid;
    int nacc = 0;
    for (int cursor = 0; cursor < (int)nc && nacc < MAXDET; cursor += 64) {
      const int c = cursor + lane;
      bool alive = (c < (int)nc);
      float c0 = 0.f, c1 = 0.f, c2 = 0.f, c3 = 0.f;
      uint32_t myidx = 0;
      if (alive) {
        c0 = sbox[c][0]; c1 = sbox[c][1]; c2 = sbox[c][2]; c3 = sbox[c][3];
        myidx = sidx[c];
      }
      const float area_b = (c2 - c0) * (c3 - c1);

      // test chunk vs all accepted so far (float4 broadcast reads)
#pragma unroll 2
      for (int a = 0; a < nacc; a++) {
        float4 ar = accb[a];
        float area_r = (ar.z - ar.x) * (ar.w - ar.y);
        float ih = fmaxf(0.f, fminf(ar.z, c2) - fmaxf(ar.x, c0));
        float iw = fmaxf(0.f, fminf(ar.w, c3) - fmaxf(ar.y, c1));
        float inter = ih * iw;
        float uni = area_r + area_b - inter;
        bool okk = (area_r > 0.f) && (area_b > 0.f) && (uni > 0.f);
        float iou = okk ? (inter / uni) : 0.f;
        if (iou > 0.5f) alive = false;
      }

      unsigned long long am = __ballot(alive);
      while (am != 0ULL && nacc < MAXDET) {
        int L = (int)(__ffsll(am) - 1);
        float r0 = __shfl(c0, L), r1 = __shfl(c1, L);
        float r2 = __shfl(c2, L), r3 = __shfl(c3, L);
        uint32_t ridx = (uint32_t)__shfl((int)myidx, L);
        if (lane == 0) {
          pick_i[nacc] = ridx;
          accb[nacc] = make_float4(r0, r1, r2, r3);
        }
        asm volatile("s_waitcnt lgkmcnt(0)" ::: "memory");
        if (lane == L) alive = false;
        if (alive) {
          float area_r = (r2 - r0) * (r3 - r1);
          float ih = fmaxf(0.f, fminf(r2, c2) - fmaxf(r0, c0));
          float iw = fmaxf(0.f, fminf(r3, c3) - fmaxf(r1, c1));
          float inter = ih * iw;
          float uni = area_r + area_b - inter;
          bool okk = (area_r > 0.f) && (area_b > 0.f) && (uni > 0.f);
          float iou = okk ? (inter / uni) : 0.f;
          if (iou > 0.5f) alive = false;
        }
        am = __ballot(alive);
        nacc++;
      }
    }
    if (lane == 0) nacc_sh = nacc;
  }
  __syncthreads();

  // -------- fused output phase: threads 0..MAXDET-1 each own one pick slot ----
  const int nacc = nacc_sh;
  if (tid >= MAXDET) return;
  const int r = b * MAXDET + tid;
  float* boxes_out  = out;
  float* clsidx_out = out + BATCH * MAXDET * 4;
  float* cls_out    = out + BATCH * MAXDET * 4 + BATCH * MAXDET;

  if (tid >= nacc) {
    boxes_out[r * 4 + 0] = 0.f; boxes_out[r * 4 + 1] = 0.f;
    boxes_out[r * 4 + 2] = 0.f; boxes_out[r * 4 + 3] = 0.f;
    clsidx_out[r] = 0.f;
    for (int j = 0; j < NCLS; j++) cls_out[r * NCLS + j] = 0.f;
    return;
  }
  float4 bb = accb[tid];
  boxes_out[r * 4 + 0] = bb.x;
  boxes_out[r * 4 + 1] = bb.y;
  boxes_out[r * 4 + 2] = bb.z;
  boxes_out[r * 4 + 3] = bb.w;

  uint32_t idx = pick_i[tid];
  const float4* p = (const float4*)(cls + ((size_t)b * N + idx) * NCLS);
  float x[NCLS];
#pragma unroll
  for (int i = 0; i < NCLS / 4; i++) {
    float4 v = p[i];
    x[4 * i] = v.x; x[4 * i + 1] = v.y; x[4 * i + 2] = v.z; x[4 * i + 3] = v.w;
  }
  float m = x[0];
#pragma unroll
  for (int i = 1; i < NCLS; i++) m = fmaxf(m, x[i]);
  float r8[8];
#pragma unroll
  for (int j = 0; j < 8; j++) r8[j] = 0.0f;
#pragma unroll
  for (int i = 0; i < NCLS / 8; i++)
#pragma unroll
    for (int j = 0; j < 8; j++) r8[j] += expf(x[i * 8 + j] - m);
  float s = ((r8[0] + r8[1]) + (r8[2] + r8[3])) + ((r8[4] + r8[5]) + (r8[6] + r8[7]));

  float best = -1.f; int bi = 0;
  for (int j = 0; j < NCLS; j++) {
    float pj = expf(x[j] - m) / s;
    cls_out[r * NCLS + j] = pj;
    if (pj > best) { best = pj; bi = j; }
  }
  clsidx_out[r] = (float)bi;
}

extern "C" void kernel_launch(void* const* d_in, const int* in_sizes, int n_in,
                              void* d_out, int out_size, void* d_ws, size_t ws_size,
                              hipStream_t stream) {
  (void)n_in; (void)out_size; (void)ws_size;
  const float* box = (const float*)d_in[0];
  const float* cls = (const float*)d_in[1];
  const int N = in_sizes[0] / (BATCH * 4);
  const int BN = BATCH * N;

  float*    ws_scores = (float*)d_ws;                          // BN floats
  uint32_t* ctr   = (uint32_t*)(ws_scores + (size_t)BN);       // BATCH
  uint32_t* Tb    = ctr + BATCH;                               // BATCH
  uint32_t* csb   = Tb + BATCH;                                // BATCH*CAP
  uint32_t* cidx  = csb + BATCH * CAP;                         // BATCH*CAP

  {
    long long tot = (long long)BN * 2;
    int blocks = (int)((tot + 255) / 256);
    scores_kernel<<<blocks, 256, 0, stream>>>(cls, ws_scores, BN);
  }
  histthresh_kernel<<<BATCH, HT_THREADS, 0, stream>>>(ws_scores, Tb, ctr, N);
  dim3 cgrid((N + 1023) / 1024, BATCH);
  compact_kernel<<<cgrid, 1024, 0, stream>>>(ws_scores, Tb, ctr, csb, cidx, N);
  nmsout_kernel<<<BATCH, 256, 0, stream>>>(box, cls, csb, cidx, ctr,
                                           (float*)d_out, N);
}